// Round 1
// baseline (485.064 us; speedup 1.0000x reference)
//
#include <hip/hip_runtime.h>
#include <hip/hip_bf16.h>
#include <cstddef>

#define N_NODES 50000
#define IN_DIM 256
#define HID_DIM 64
#define OUT_DIM 40
#define N_EDGES 800000

// ---------------------------------------------------------------------------
// K1: degree count over dst (self-loop added later as +1 in k_dinv)
__global__ void k_deg(const int* __restrict__ dst, float* __restrict__ deg, int E) {
    int i = blockIdx.x * blockDim.x + threadIdx.x;
    if (i < E) atomicAdd(&deg[dst[i]], 1.0f);
}

// K2: dinv = rsqrt(deg + 1)   (+1 = self loop; always > 0)
__global__ void k_dinv(float* __restrict__ deg, int N) {
    int i = blockIdx.x * blockDim.x + threadIdx.x;
    if (i < N) deg[i] = rsqrtf(deg[i] + 1.0f);
}

// K3: h1 = x @ W1   [50000,256]x[256,64]; 16 rows per block, LDS-staged x tile
__global__ __launch_bounds__(256) void k_gemm1(const float* __restrict__ x,
                                               const float* __restrict__ W1,
                                               float* __restrict__ h1) {
    __shared__ float xs[16][IN_DIM];              // 16 KB
    int row0 = blockIdx.x * 16;                   // 50000 % 16 == 0 -> 3125 blocks
    const float4* xv = (const float4*)(x + (size_t)row0 * IN_DIM);
    float4* xsv = (float4*)&xs[0][0];
    for (int i = threadIdx.x; i < 16 * IN_DIM / 4; i += 256) xsv[i] = xv[i];
    __syncthreads();
    int c  = threadIdx.x & 63;                    // output column 0..63
    int rg = threadIdx.x >> 6;                    // row group 0..3 (4 rows each)
    float acc0 = 0.f, acc1 = 0.f, acc2 = 0.f, acc3 = 0.f;
    for (int k = 0; k < IN_DIM; ++k) {
        float w = W1[k * HID_DIM + c];            // coalesced across lanes, L2-hot
        acc0 += xs[rg * 4 + 0][k] * w;            // LDS broadcast (no conflict)
        acc1 += xs[rg * 4 + 1][k] * w;
        acc2 += xs[rg * 4 + 2][k] * w;
        acc3 += xs[rg * 4 + 3][k] * w;
    }
    size_t base = ((size_t)row0 + rg * 4) * HID_DIM + c;
    h1[base + 0 * HID_DIM] = acc0;
    h1[base + 1 * HID_DIM] = acc1;
    h1[base + 2 * HID_DIM] = acc2;
    h1[base + 3 * HID_DIM] = acc3;
}

// K4/K7: normalized scatter-add. One 64-lane wave per edge; lane = channel.
// Virtual edges e in [E, E+N) are the self-loops (s = d = e - E).
template <int DIM>
__global__ void k_scatter(const int* __restrict__ src, const int* __restrict__ dst,
                          const float* __restrict__ dinv, const float* __restrict__ h,
                          float* __restrict__ out, int E) {
    int wid  = (int)((blockIdx.x * (size_t)blockDim.x + threadIdx.x) >> 6);
    int lane = threadIdx.x & 63;
    int total = E + N_NODES;
    if (wid >= total) return;
    int s, d;
    if (wid < E) { s = src[wid]; d = dst[wid]; }
    else         { s = d = wid - E; }
    float w = dinv[s] * dinv[d];
    if (lane < DIM) {
        float v = h[(size_t)s * DIM + lane] * w;
        atomicAdd(&out[(size_t)d * DIM + lane], v);
    }
}

// K5: in-place bias + relu on agg1
__global__ void k_bias_relu(float* __restrict__ a, const float* __restrict__ b, int total) {
    int i = blockIdx.x * blockDim.x + threadIdx.x;
    if (i < total) {
        int c = i & (HID_DIM - 1);
        a[i] = fmaxf(a[i] + b[c], 0.f);
    }
}

// K6: h2 = a @ W2   [50000,64]x[64,40] — thread per output element (tiny GEMM)
__global__ void k_gemm2(const float* __restrict__ a, const float* __restrict__ W2,
                        float* __restrict__ h2) {
    int idx = blockIdx.x * blockDim.x + threadIdx.x;
    if (idx >= N_NODES * OUT_DIM) return;
    int row = idx / OUT_DIM;
    int col = idx - row * OUT_DIM;
    const float* ar = a + (size_t)row * HID_DIM;
    float acc = 0.f;
#pragma unroll
    for (int k = 0; k < HID_DIM; ++k) acc += ar[k] * W2[k * OUT_DIM + col];
    h2[idx] = acc;
}

// K8: out = log_softmax(out + b2) per row of 40; one wave per row
__global__ void k_logsoftmax(float* __restrict__ out, const float* __restrict__ b2) {
    int wid  = (int)((blockIdx.x * (size_t)blockDim.x + threadIdx.x) >> 6);
    int lane = threadIdx.x & 63;
    if (wid >= N_NODES) return;
    float* row = out + (size_t)wid * OUT_DIM;
    float v = -INFINITY;
    if (lane < OUT_DIM) v = row[lane] + b2[lane];
    float m = v;
    for (int o = 32; o; o >>= 1) m = fmaxf(m, __shfl_xor(m, o));
    float ex = (lane < OUT_DIM) ? __expf(v - m) : 0.f;
    float s = ex;
    for (int o = 32; o; o >>= 1) s += __shfl_xor(s, o);
    float ls = __logf(s);
    if (lane < OUT_DIM) row[lane] = v - m - ls;
}

extern "C" void kernel_launch(void* const* d_in, const int* in_sizes, int n_in,
                              void* d_out, int out_size, void* d_ws, size_t ws_size,
                              hipStream_t stream) {
    const float* x    = (const float*)d_in[0];
    const int*   ei   = (const int*)d_in[1];
    const int*   srcp = ei;             // edge_index[0]
    const int*   dstp = ei + N_EDGES;   // edge_index[1]
    const float* W1   = (const float*)d_in[2];
    const float* b1   = (const float*)d_in[3];
    const float* W2   = (const float*)d_in[4];
    const float* b2   = (const float*)d_in[5];
    float* out = (float*)d_out;

    // workspace layout (floats): dinv | h1 | agg1 | h2   (~33.8 MB)
    float* dinv = (float*)d_ws;
    float* h1   = dinv + N_NODES;
    float* agg1 = h1 + (size_t)N_NODES * HID_DIM;
    float* h2   = agg1 + (size_t)N_NODES * HID_DIM;

    hipMemsetAsync(dinv, 0, N_NODES * sizeof(float), stream);
    hipMemsetAsync(agg1, 0, (size_t)N_NODES * HID_DIM * sizeof(float), stream);
    hipMemsetAsync(out, 0, (size_t)N_NODES * OUT_DIM * sizeof(float), stream);

    k_deg<<<(N_EDGES + 255) / 256, 256, 0, stream>>>(dstp, dinv, N_EDGES);
    k_dinv<<<(N_NODES + 255) / 256, 256, 0, stream>>>(dinv, N_NODES);

    k_gemm1<<<N_NODES / 16, 256, 0, stream>>>(x, W1, h1);

    int total_e = N_EDGES + N_NODES;           // real edges + self loops
    int blocks_e = (total_e + 3) / 4;          // 4 waves (edges) per 256-thread block
    k_scatter<HID_DIM><<<blocks_e, 256, 0, stream>>>(srcp, dstp, dinv, h1, agg1, N_EDGES);

    k_bias_relu<<<(N_NODES * HID_DIM + 255) / 256, 256, 0, stream>>>(agg1, b1, N_NODES * HID_DIM);

    k_gemm2<<<(N_NODES * OUT_DIM + 255) / 256, 256, 0, stream>>>(agg1, W2, h2);

    k_scatter<OUT_DIM><<<blocks_e, 256, 0, stream>>>(srcp, dstp, dinv, h2, out, N_EDGES);

    k_logsoftmax<<<(N_NODES + 3) / 4, 256, 0, stream>>>(out, b2);
}

// Round 2
// 259.005 us; speedup vs baseline: 1.8728x; 1.8728x over previous
//
#include <hip/hip_runtime.h>
#include <hip/hip_bf16.h>
#include <cstddef>

#define N_NODES 50000
#define IN_DIM 256
#define HID_DIM 64
#define OUT_DIM 40
#define N_EDGES 800000

// ---------------------------------------------------------------------------
// K1: int degree histogram over dst (self-loop handled as +1 later)
__global__ void k_count(const int* __restrict__ dst, int* __restrict__ cnt, int E) {
    int i = blockIdx.x * blockDim.x + threadIdx.x;
    if (i < E) atomicAdd(&cnt[dst[i]], 1);
}

// K2a: per-block exclusive scan of cnt -> excl (block-local) + block sums
__global__ void k_scan1(const int* __restrict__ cnt, int* __restrict__ excl,
                        int* __restrict__ bsum) {
    __shared__ int wsum[4];
    int i = blockIdx.x * 256 + threadIdx.x;
    int lane = threadIdx.x & 63, w = threadIdx.x >> 6;
    int v = (i < N_NODES) ? cnt[i] : 0;
    int inc = v;
    for (int o = 1; o < 64; o <<= 1) {
        int t = __shfl_up(inc, o);
        if (lane >= o) inc += t;
    }
    if (lane == 63) wsum[w] = inc;
    __syncthreads();
    int off = 0;
    for (int k = 0; k < w; ++k) off += wsum[k];
    if (i < N_NODES) excl[i] = off + inc - v;
    if (threadIdx.x == 255) bsum[blockIdx.x] = off + inc;
}

// K2b: single-block exclusive scan of the block sums (nb <= 256)
__global__ void k_scan2(int* __restrict__ bsum, int nb) {
    __shared__ int wsum[4];
    int i = threadIdx.x;
    int lane = i & 63, w = i >> 6;
    int v = (i < nb) ? bsum[i] : 0;
    int inc = v;
    for (int o = 1; o < 64; o <<= 1) {
        int t = __shfl_up(inc, o);
        if (lane >= o) inc += t;
    }
    if (lane == 63) wsum[w] = inc;
    __syncthreads();
    int off = 0;
    for (int k = 0; k < w; ++k) off += wsum[k];
    if (i < nb) bsum[i] = off + inc - v;
}

// K2c: add block offsets; append rowptr[N] = E
__global__ void k_scan3(int* __restrict__ rowptr, const int* __restrict__ bsum) {
    int i = blockIdx.x * 256 + threadIdx.x;
    if (i < N_NODES) rowptr[i] += bsum[blockIdx.x];
    else if (i == N_NODES) rowptr[i] = N_EDGES;
}

// K3: dinv = rsqrt(deg + 1)
__global__ void k_dinv(const int* __restrict__ cnt, float* __restrict__ dinv, int N) {
    int i = blockIdx.x * blockDim.x + threadIdx.x;
    if (i < N) dinv[i] = rsqrtf((float)cnt[i] + 1.0f);
}

// K4: bucket fill — esrc[rowptr[d] + k] = src of k-th incoming edge of d
__global__ void k_fill(const int* __restrict__ src, const int* __restrict__ dst,
                       const int* __restrict__ rowptr, int* __restrict__ cursor,
                       int* __restrict__ esrc, int E) {
    int i = blockIdx.x * blockDim.x + threadIdx.x;
    if (i < E) {
        int d = dst[i];
        int p = rowptr[d] + atomicAdd(&cursor[d], 1);
        esrc[p] = src[i];
    }
}

// K5: h1 = x @ W1   [50000,256]x[256,64]; 16 rows per block, LDS-staged x tile
__global__ __launch_bounds__(256) void k_gemm1(const float* __restrict__ x,
                                               const float* __restrict__ W1,
                                               float* __restrict__ h1) {
    __shared__ float xs[16][IN_DIM];              // 16 KB
    int row0 = blockIdx.x * 16;
    const float4* xv = (const float4*)(x + (size_t)row0 * IN_DIM);
    float4* xsv = (float4*)&xs[0][0];
    for (int i = threadIdx.x; i < 16 * IN_DIM / 4; i += 256) xsv[i] = xv[i];
    __syncthreads();
    int c  = threadIdx.x & 63;
    int rg = threadIdx.x >> 6;
    float acc0 = 0.f, acc1 = 0.f, acc2 = 0.f, acc3 = 0.f;
    for (int k = 0; k < IN_DIM; ++k) {
        float w = W1[k * HID_DIM + c];
        acc0 += xs[rg * 4 + 0][k] * w;
        acc1 += xs[rg * 4 + 1][k] * w;
        acc2 += xs[rg * 4 + 2][k] * w;
        acc3 += xs[rg * 4 + 3][k] * w;
    }
    size_t base = ((size_t)row0 + rg * 4) * HID_DIM + c;
    h1[base + 0 * HID_DIM] = acc0;
    h1[base + 1 * HID_DIM] = acc1;
    h1[base + 2 * HID_DIM] = acc2;
    h1[base + 3 * HID_DIM] = acc3;
}

// K6: gather-side aggregation, DIM=64, fused bias+ReLU. One wave per node.
__global__ __launch_bounds__(256) void k_agg_relu(const int* __restrict__ rowptr,
        const int* __restrict__ esrc, const float* __restrict__ dinv,
        const float* __restrict__ h, const float* __restrict__ b,
        float* __restrict__ out) {
    int wid  = (int)((blockIdx.x * (size_t)blockDim.x + threadIdx.x) >> 6);
    int lane = threadIdx.x & 63;
    if (wid >= N_NODES) return;
    float dd = dinv[wid];
    float acc = h[(size_t)wid * HID_DIM + lane] * dd * dd;   // self-loop
    int beg = rowptr[wid], end = rowptr[wid + 1];
    int j = beg;
    for (; j + 4 <= end; j += 4) {
        int s0 = esrc[j], s1 = esrc[j + 1], s2 = esrc[j + 2], s3 = esrc[j + 3];
        float w0 = dinv[s0] * dd, w1 = dinv[s1] * dd;
        float w2 = dinv[s2] * dd, w3 = dinv[s3] * dd;
        acc += h[(size_t)s0 * HID_DIM + lane] * w0;
        acc += h[(size_t)s1 * HID_DIM + lane] * w1;
        acc += h[(size_t)s2 * HID_DIM + lane] * w2;
        acc += h[(size_t)s3 * HID_DIM + lane] * w3;
    }
    for (; j < end; ++j) {
        int s = esrc[j];
        acc += h[(size_t)s * HID_DIM + lane] * (dinv[s] * dd);
    }
    out[(size_t)wid * HID_DIM + lane] = fmaxf(acc + b[lane], 0.f);
}

// K7: h2 = a @ W2   [50000,64]x[64,40] — thread per output element
__global__ void k_gemm2(const float* __restrict__ a, const float* __restrict__ W2,
                        float* __restrict__ h2) {
    int idx = blockIdx.x * blockDim.x + threadIdx.x;
    if (idx >= N_NODES * OUT_DIM) return;
    int row = idx / OUT_DIM;
    int col = idx - row * OUT_DIM;
    const float* ar = a + (size_t)row * HID_DIM;
    float acc = 0.f;
#pragma unroll
    for (int k = 0; k < HID_DIM; ++k) acc += ar[k] * W2[k * OUT_DIM + col];
    h2[idx] = acc;
}

// K8: gather aggregation DIM=40, fused bias + log_softmax. One wave per node.
__global__ __launch_bounds__(256) void k_agg_lsm(const int* __restrict__ rowptr,
        const int* __restrict__ esrc, const float* __restrict__ dinv,
        const float* __restrict__ h, const float* __restrict__ b,
        float* __restrict__ out) {
    int wid  = (int)((blockIdx.x * (size_t)blockDim.x + threadIdx.x) >> 6);
    int lane = threadIdx.x & 63;
    if (wid >= N_NODES) return;
    float dd = dinv[wid];
    float acc = 0.f;
    if (lane < OUT_DIM) acc = h[(size_t)wid * OUT_DIM + lane] * dd * dd;
    int beg = rowptr[wid], end = rowptr[wid + 1];
    int j = beg;
    for (; j + 4 <= end; j += 4) {
        int s0 = esrc[j], s1 = esrc[j + 1], s2 = esrc[j + 2], s3 = esrc[j + 3];
        float w0 = dinv[s0] * dd, w1 = dinv[s1] * dd;
        float w2 = dinv[s2] * dd, w3 = dinv[s3] * dd;
        if (lane < OUT_DIM) {
            acc += h[(size_t)s0 * OUT_DIM + lane] * w0;
            acc += h[(size_t)s1 * OUT_DIM + lane] * w1;
            acc += h[(size_t)s2 * OUT_DIM + lane] * w2;
            acc += h[(size_t)s3 * OUT_DIM + lane] * w3;
        }
    }
    for (; j < end; ++j) {
        int s = esrc[j];
        if (lane < OUT_DIM) acc += h[(size_t)s * OUT_DIM + lane] * (dinv[s] * dd);
    }
    float v = (lane < OUT_DIM) ? acc + b[lane] : -INFINITY;
    float m = v;
    for (int o = 32; o; o >>= 1) m = fmaxf(m, __shfl_xor(m, o));
    float ex = (lane < OUT_DIM) ? __expf(v - m) : 0.f;
    float s = ex;
    for (int o = 32; o; o >>= 1) s += __shfl_xor(s, o);
    float ls = __logf(s);
    if (lane < OUT_DIM) out[(size_t)wid * OUT_DIM + lane] = v - m - ls;
}

extern "C" void kernel_launch(void* const* d_in, const int* in_sizes, int n_in,
                              void* d_out, int out_size, void* d_ws, size_t ws_size,
                              hipStream_t stream) {
    const float* x    = (const float*)d_in[0];
    const int*   ei   = (const int*)d_in[1];
    const int*   srcp = ei;             // edge_index[0]
    const int*   dstp = ei + N_EDGES;   // edge_index[1]
    const float* W1   = (const float*)d_in[2];
    const float* b1   = (const float*)d_in[3];
    const float* W2   = (const float*)d_in[4];
    const float* b2   = (const float*)d_in[5];
    float* out = (float*)d_out;

    // workspace layout (~37.7 MB)
    char* p = (char*)d_ws;
    int*   cnt    = (int*)p;   p += (size_t)N_NODES * 4;
    int*   rowptr = (int*)p;   p += (size_t)(N_NODES + 4) * 4;   // padded
    int*   cursor = (int*)p;   p += (size_t)N_NODES * 4;
    int*   bsum   = (int*)p;   p += 256 * 4;
    int*   esrc   = (int*)p;   p += (size_t)N_EDGES * 4;
    float* dinv   = (float*)p; p += (size_t)N_NODES * 4;
    float* h1     = (float*)p; p += (size_t)N_NODES * HID_DIM * 4;
    float* agg1   = (float*)p; p += (size_t)N_NODES * HID_DIM * 4;
    float* h2     = (float*)p; p += (size_t)N_NODES * OUT_DIM * 4;

    hipMemsetAsync(cnt, 0, (size_t)N_NODES * 4, stream);
    hipMemsetAsync(cursor, 0, (size_t)N_NODES * 4, stream);

    const int NBLK = (N_NODES + 255) / 256;  // 196

    k_count<<<(N_EDGES + 255) / 256, 256, 0, stream>>>(dstp, cnt, N_EDGES);
    k_scan1<<<NBLK, 256, 0, stream>>>(cnt, rowptr, bsum);
    k_scan2<<<1, 256, 0, stream>>>(bsum, NBLK);
    k_scan3<<<NBLK, 256, 0, stream>>>(rowptr, bsum);
    k_dinv<<<(N_NODES + 255) / 256, 256, 0, stream>>>(cnt, dinv, N_NODES);
    k_fill<<<(N_EDGES + 255) / 256, 256, 0, stream>>>(srcp, dstp, rowptr, cursor, esrc, N_EDGES);

    k_gemm1<<<N_NODES / 16, 256, 0, stream>>>(x, W1, h1);

    k_agg_relu<<<(N_NODES + 3) / 4, 256, 0, stream>>>(rowptr, esrc, dinv, h1, b1, agg1);

    k_gemm2<<<(N_NODES * OUT_DIM + 255) / 256, 256, 0, stream>>>(agg1, W2, h2);

    k_agg_lsm<<<(N_NODES + 3) / 4, 256, 0, stream>>>(rowptr, esrc, dinv, h2, b2, out);
}

// Round 3
// 203.467 us; speedup vs baseline: 2.3840x; 1.2730x over previous
//
#include <hip/hip_runtime.h>
#include <hip/hip_bf16.h>
#include <cstddef>

#define N_NODES 50000
#define IN_DIM 256
#define HID_DIM 64
#define OUT_DIM 40
#define N_EDGES 800000

// ---------------------------------------------------------------------------
// K1: degree histogram over dst; atomicAdd return value = rank of edge in its
// dst bucket (saves the second atomic pass in fill).
__global__ void k_count(const int* __restrict__ dst, int* __restrict__ cnt,
                        int* __restrict__ rank_, int E) {
    int i = blockIdx.x * blockDim.x + threadIdx.x;
    if (i < E) rank_[i] = atomicAdd(&cnt[dst[i]], 1);
}

// K2a: per-block exclusive scan of cnt -> rowptr (block-local) + block sums
__global__ void k_scan1(const int* __restrict__ cnt, int* __restrict__ excl,
                        int* __restrict__ bsum) {
    __shared__ int wsum[4];
    int i = blockIdx.x * 256 + threadIdx.x;
    int lane = threadIdx.x & 63, w = threadIdx.x >> 6;
    int v = (i < N_NODES) ? cnt[i] : 0;
    int inc = v;
    for (int o = 1; o < 64; o <<= 1) {
        int t = __shfl_up(inc, o);
        if (lane >= o) inc += t;
    }
    if (lane == 63) wsum[w] = inc;
    __syncthreads();
    int off = 0;
    for (int k = 0; k < w; ++k) off += wsum[k];
    if (i < N_NODES) excl[i] = off + inc - v;
    if (threadIdx.x == 255) bsum[blockIdx.x] = off + inc;
}

// K2b: single-block exclusive scan of the block sums (nb <= 256)
__global__ void k_scan2(int* __restrict__ bsum, int nb) {
    __shared__ int wsum[4];
    int i = threadIdx.x;
    int lane = i & 63, w = i >> 6;
    int v = (i < nb) ? bsum[i] : 0;
    int inc = v;
    for (int o = 1; o < 64; o <<= 1) {
        int t = __shfl_up(inc, o);
        if (lane >= o) inc += t;
    }
    if (lane == 63) wsum[w] = inc;
    __syncthreads();
    int off = 0;
    for (int k = 0; k < w; ++k) off += wsum[k];
    if (i < nb) bsum[i] = off + inc - v;
}

// K2c: add block offsets; append rowptr[N] = E; also dinv = rsqrt(deg+1)
__global__ void k_scan3_dinv(int* __restrict__ rowptr, const int* __restrict__ bsum,
                             const int* __restrict__ cnt, float* __restrict__ dinv) {
    int i = blockIdx.x * 256 + threadIdx.x;
    if (i < N_NODES) {
        rowptr[i] += bsum[blockIdx.x];
        dinv[i] = rsqrtf((float)cnt[i] + 1.0f);
    } else if (i == N_NODES) {
        rowptr[i] = N_EDGES;
    }
}

// K3: atomic-free bucket fill using precomputed rank
__global__ void k_fill(const int* __restrict__ src, const int* __restrict__ dst,
                       const int* __restrict__ rowptr, const int* __restrict__ rank_,
                       int* __restrict__ esrc, int E) {
    int i = blockIdx.x * blockDim.x + threadIdx.x;
    if (i < E) {
        int d = dst[i];
        esrc[rowptr[d] + rank_[i]] = src[i];
    }
}

// K4: h1 = x @ W1  [50000,256]x[256,64]
// 64x64 tile per 256-thread block; each thread 4 rows x 4 cols; BK=32.
// xsT staged transposed (pad 4 -> bank-spread, 16B-aligned b128 reads).
__global__ __launch_bounds__(256) void k_gemm1(const float* __restrict__ x,
                                               const float* __restrict__ W1,
                                               float* __restrict__ h1) {
    __shared__ float xsT[32][68];   // [k][row], padded
    __shared__ float ws[32][64];    // [k][col]
    const int tid = threadIdx.x;
    const int row0 = blockIdx.x * 64;
    const int rbase = (tid >> 4) * 4;   // 0..60
    const int cbase = (tid & 15) * 4;   // 0..60
    float acc[4][4] = {};

    for (int k0 = 0; k0 < IN_DIM; k0 += 32) {
        __syncthreads();
#pragma unroll
        for (int q = 0; q < 2; ++q) {            // stage x tile (transposed)
            int fid = q * 256 + tid;             // 0..511
            int row = fid >> 3, kq = fid & 7;
            int grow = row0 + row;
            float4 v = make_float4(0.f, 0.f, 0.f, 0.f);
            if (grow < N_NODES)
                v = *(const float4*)&x[(size_t)grow * IN_DIM + k0 + kq * 4];
            xsT[kq * 4 + 0][row] = v.x;
            xsT[kq * 4 + 1][row] = v.y;
            xsT[kq * 4 + 2][row] = v.z;
            xsT[kq * 4 + 3][row] = v.w;
        }
#pragma unroll
        for (int q = 0; q < 2; ++q) {            // stage W tile
            int fid = q * 256 + tid;
            int kr = fid >> 4, cq = fid & 15;
            *(float4*)&ws[kr][cq * 4] =
                *(const float4*)&W1[(size_t)(k0 + kr) * HID_DIM + cq * 4];
        }
        __syncthreads();
#pragma unroll
        for (int k = 0; k < 32; ++k) {
            float4 a = *(const float4*)&xsT[k][rbase];
            float4 w = *(const float4*)&ws[k][cbase];
            acc[0][0] += a.x * w.x; acc[0][1] += a.x * w.y; acc[0][2] += a.x * w.z; acc[0][3] += a.x * w.w;
            acc[1][0] += a.y * w.x; acc[1][1] += a.y * w.y; acc[1][2] += a.y * w.z; acc[1][3] += a.y * w.w;
            acc[2][0] += a.z * w.x; acc[2][1] += a.z * w.y; acc[2][2] += a.z * w.z; acc[2][3] += a.z * w.w;
            acc[3][0] += a.w * w.x; acc[3][1] += a.w * w.y; acc[3][2] += a.w * w.z; acc[3][3] += a.w * w.w;
        }
    }
#pragma unroll
    for (int i = 0; i < 4; ++i) {
        int grow = row0 + rbase + i;
        if (grow < N_NODES) {
            float4 o = make_float4(acc[i][0], acc[i][1], acc[i][2], acc[i][3]);
            *(float4*)&h1[(size_t)grow * HID_DIM + cbase] = o;
        }
    }
}

// K5: gather-side aggregation, DIM=64, fused bias+ReLU. One wave per node.
__global__ __launch_bounds__(256) void k_agg_relu(const int* __restrict__ rowptr,
        const int* __restrict__ esrc, const float* __restrict__ dinv,
        const float* __restrict__ h, const float* __restrict__ b,
        float* __restrict__ out) {
    int wid  = (int)((blockIdx.x * (size_t)blockDim.x + threadIdx.x) >> 6);
    int lane = threadIdx.x & 63;
    if (wid >= N_NODES) return;
    float dd = dinv[wid];
    float acc = h[(size_t)wid * HID_DIM + lane] * dd * dd;   // self-loop
    int beg = rowptr[wid], end = rowptr[wid + 1];
    int j = beg;
    for (; j + 4 <= end; j += 4) {
        int s0 = esrc[j], s1 = esrc[j + 1], s2 = esrc[j + 2], s3 = esrc[j + 3];
        float w0 = dinv[s0] * dd, w1 = dinv[s1] * dd;
        float w2 = dinv[s2] * dd, w3 = dinv[s3] * dd;
        acc += h[(size_t)s0 * HID_DIM + lane] * w0;
        acc += h[(size_t)s1 * HID_DIM + lane] * w1;
        acc += h[(size_t)s2 * HID_DIM + lane] * w2;
        acc += h[(size_t)s3 * HID_DIM + lane] * w3;
    }
    for (; j < end; ++j) {
        int s = esrc[j];
        acc += h[(size_t)s * HID_DIM + lane] * (dinv[s] * dd);
    }
    out[(size_t)wid * HID_DIM + lane] = fmaxf(acc + b[lane], 0.f);
}

// K6: h2 = a @ W2  [50000,64]x[64,40] — thread per (row, 4-col group)
__global__ void k_gemm2(const float* __restrict__ a, const float* __restrict__ W2,
                        float* __restrict__ h2) {
    int idx = blockIdx.x * blockDim.x + threadIdx.x;
    if (idx >= N_NODES * (OUT_DIM / 4)) return;
    int row = idx / (OUT_DIM / 4);
    int cg  = idx - row * (OUT_DIM / 4);
    const float* ar = a + (size_t)row * HID_DIM;
    float4 acc = make_float4(0.f, 0.f, 0.f, 0.f);
#pragma unroll
    for (int k = 0; k < HID_DIM; ++k) {
        float ak = ar[k];
        float4 w = *(const float4*)&W2[k * OUT_DIM + cg * 4];
        acc.x += ak * w.x; acc.y += ak * w.y; acc.z += ak * w.z; acc.w += ak * w.w;
    }
    *(float4*)&h2[(size_t)row * OUT_DIM + cg * 4] = acc;
}

// K7: gather aggregation DIM=40, fused bias + log_softmax. One wave per node.
__global__ __launch_bounds__(256) void k_agg_lsm(const int* __restrict__ rowptr,
        const int* __restrict__ esrc, const float* __restrict__ dinv,
        const float* __restrict__ h, const float* __restrict__ b,
        float* __restrict__ out) {
    int wid  = (int)((blockIdx.x * (size_t)blockDim.x + threadIdx.x) >> 6);
    int lane = threadIdx.x & 63;
    if (wid >= N_NODES) return;
    float dd = dinv[wid];
    float acc = 0.f;
    if (lane < OUT_DIM) acc = h[(size_t)wid * OUT_DIM + lane] * dd * dd;
    int beg = rowptr[wid], end = rowptr[wid + 1];
    int j = beg;
    for (; j + 4 <= end; j += 4) {
        int s0 = esrc[j], s1 = esrc[j + 1], s2 = esrc[j + 2], s3 = esrc[j + 3];
        float w0 = dinv[s0] * dd, w1 = dinv[s1] * dd;
        float w2 = dinv[s2] * dd, w3 = dinv[s3] * dd;
        if (lane < OUT_DIM) {
            acc += h[(size_t)s0 * OUT_DIM + lane] * w0;
            acc += h[(size_t)s1 * OUT_DIM + lane] * w1;
            acc += h[(size_t)s2 * OUT_DIM + lane] * w2;
            acc += h[(size_t)s3 * OUT_DIM + lane] * w3;
        }
    }
    for (; j < end; ++j) {
        int s = esrc[j];
        if (lane < OUT_DIM) acc += h[(size_t)s * OUT_DIM + lane] * (dinv[s] * dd);
    }
    float v = (lane < OUT_DIM) ? acc + b[lane] : -INFINITY;
    float m = v;
    for (int o = 32; o; o >>= 1) m = fmaxf(m, __shfl_xor(m, o));
    float ex = (lane < OUT_DIM) ? __expf(v - m) : 0.f;
    float s = ex;
    for (int o = 32; o; o >>= 1) s += __shfl_xor(s, o);
    float ls = __logf(s);
    if (lane < OUT_DIM) out[(size_t)wid * OUT_DIM + lane] = v - m - ls;
}

extern "C" void kernel_launch(void* const* d_in, const int* in_sizes, int n_in,
                              void* d_out, int out_size, void* d_ws, size_t ws_size,
                              hipStream_t stream) {
    const float* x    = (const float*)d_in[0];
    const int*   ei   = (const int*)d_in[1];
    const int*   srcp = ei;             // edge_index[0]
    const int*   dstp = ei + N_EDGES;   // edge_index[1]
    const float* W1   = (const float*)d_in[2];
    const float* b1   = (const float*)d_in[3];
    const float* W2   = (const float*)d_in[4];
    const float* b2   = (const float*)d_in[5];
    float* out = (float*)d_out;

    // workspace layout (~41 MB)
    char* p = (char*)d_ws;
    int*   cnt    = (int*)p;   p += (size_t)N_NODES * 4;
    int*   rowptr = (int*)p;   p += (size_t)(N_NODES + 4) * 4;
    int*   rank_  = (int*)p;   p += (size_t)N_EDGES * 4;
    int*   bsum   = (int*)p;   p += 256 * 4;
    int*   esrc   = (int*)p;   p += (size_t)N_EDGES * 4;
    float* dinv   = (float*)p; p += (size_t)N_NODES * 4;
    float* h1     = (float*)p; p += (size_t)N_NODES * HID_DIM * 4;
    float* agg1   = (float*)p; p += (size_t)N_NODES * HID_DIM * 4;
    float* h2     = (float*)p; p += (size_t)N_NODES * OUT_DIM * 4;

    hipMemsetAsync(cnt, 0, (size_t)N_NODES * 4, stream);

    const int NBLK = (N_NODES + 255) / 256;  // 196

    k_count<<<(N_EDGES + 255) / 256, 256, 0, stream>>>(dstp, cnt, rank_, N_EDGES);
    k_scan1<<<NBLK, 256, 0, stream>>>(cnt, rowptr, bsum);
    k_scan2<<<1, 256, 0, stream>>>(bsum, NBLK);
    k_scan3_dinv<<<NBLK, 256, 0, stream>>>(rowptr, bsum, cnt, dinv);
    k_fill<<<(N_EDGES + 255) / 256, 256, 0, stream>>>(srcp, dstp, rowptr, rank_, esrc, N_EDGES);

    k_gemm1<<<(N_NODES + 63) / 64, 256, 0, stream>>>(x, W1, h1);

    k_agg_relu<<<(N_NODES + 3) / 4, 256, 0, stream>>>(rowptr, esrc, dinv, h1, b1, agg1);

    k_gemm2<<<(N_NODES * (OUT_DIM / 4) + 255) / 256, 256, 0, stream>>>(agg1, W2, h2);

    k_agg_lsm<<<(N_NODES + 3) / 4, 256, 0, stream>>>(rowptr, esrc, dinv, h2, b2, out);
}

// Round 4
// 192.814 us; speedup vs baseline: 2.5157x; 1.0552x over previous
//
#include <hip/hip_runtime.h>
#include <hip/hip_bf16.h>
#include <hip/hip_fp16.h>
#include <cstddef>

#define N_NODES 50000
#define IN_DIM 256
#define HID_DIM 64
#define OUT_DIM 40
#define N_EDGES 800000

// ---------------------------------------------------------------------------
// K1: degree histogram over dst; atomicAdd return value = rank of edge in its
// dst bucket (saves a second atomic pass in fill).
__global__ void k_count(const int* __restrict__ dst, int* __restrict__ cnt,
                        int* __restrict__ rank_, int E) {
    int i = blockIdx.x * blockDim.x + threadIdx.x;
    if (i < E) rank_[i] = atomicAdd(&cnt[dst[i]], 1);
}

// K2a: per-block exclusive scan of cnt -> rowptr (block-local) + block sums
__global__ void k_scan1(const int* __restrict__ cnt, int* __restrict__ excl,
                        int* __restrict__ bsum) {
    __shared__ int wsum[4];
    int i = blockIdx.x * 256 + threadIdx.x;
    int lane = threadIdx.x & 63, w = threadIdx.x >> 6;
    int v = (i < N_NODES) ? cnt[i] : 0;
    int inc = v;
    for (int o = 1; o < 64; o <<= 1) {
        int t = __shfl_up(inc, o);
        if (lane >= o) inc += t;
    }
    if (lane == 63) wsum[w] = inc;
    __syncthreads();
    int off = 0;
    for (int k = 0; k < w; ++k) off += wsum[k];
    if (i < N_NODES) excl[i] = off + inc - v;
    if (threadIdx.x == 255) bsum[blockIdx.x] = off + inc;
}

// K2b: single-block exclusive scan of the block sums (nb <= 256)
__global__ void k_scan2(int* __restrict__ bsum, int nb) {
    __shared__ int wsum[4];
    int i = threadIdx.x;
    int lane = i & 63, w = i >> 6;
    int v = (i < nb) ? bsum[i] : 0;
    int inc = v;
    for (int o = 1; o < 64; o <<= 1) {
        int t = __shfl_up(inc, o);
        if (lane >= o) inc += t;
    }
    if (lane == 63) wsum[w] = inc;
    __syncthreads();
    int off = 0;
    for (int k = 0; k < w; ++k) off += wsum[k];
    if (i < nb) bsum[i] = off + inc - v;
}

// K2c: add block offsets; append rowptr[N] = E; also dinv = rsqrt(deg+1)
__global__ void k_scan3_dinv(int* __restrict__ rowptr, const int* __restrict__ bsum,
                             const int* __restrict__ cnt, float* __restrict__ dinv) {
    int i = blockIdx.x * 256 + threadIdx.x;
    if (i < N_NODES) {
        rowptr[i] += bsum[blockIdx.x];
        dinv[i] = rsqrtf((float)cnt[i] + 1.0f);
    } else if (i == N_NODES) {
        rowptr[i] = N_EDGES;
    }
}

// K3: atomic-free bucket fill using precomputed rank
__global__ void k_fill(const int* __restrict__ src, const int* __restrict__ dst,
                       const int* __restrict__ rowptr, const int* __restrict__ rank_,
                       int* __restrict__ esrc, int E) {
    int i = blockIdx.x * blockDim.x + threadIdx.x;
    if (i < E) {
        int d = dst[i];
        esrc[rowptr[d] + rank_[i]] = src[i];
    }
}

// K4: h1 = x @ W1  [50000,256]x[256,64], fp16 output.
// 64x64 tile per 256-thread block; each thread 4 rows x 4 cols; BK=32.
__global__ __launch_bounds__(256) void k_gemm1(const float* __restrict__ x,
                                               const float* __restrict__ W1,
                                               __half* __restrict__ h1) {
    __shared__ float xsT[32][68];   // [k][row], padded
    __shared__ float ws[32][64];    // [k][col]
    const int tid = threadIdx.x;
    const int row0 = blockIdx.x * 64;
    const int rbase = (tid >> 4) * 4;   // 0..60
    const int cbase = (tid & 15) * 4;   // 0..60
    float acc[4][4] = {};

    for (int k0 = 0; k0 < IN_DIM; k0 += 32) {
        __syncthreads();
#pragma unroll
        for (int q = 0; q < 2; ++q) {            // stage x tile (transposed)
            int fid = q * 256 + tid;             // 0..511
            int row = fid >> 3, kq = fid & 7;
            int grow = row0 + row;
            float4 v = make_float4(0.f, 0.f, 0.f, 0.f);
            if (grow < N_NODES)
                v = *(const float4*)&x[(size_t)grow * IN_DIM + k0 + kq * 4];
            xsT[kq * 4 + 0][row] = v.x;
            xsT[kq * 4 + 1][row] = v.y;
            xsT[kq * 4 + 2][row] = v.z;
            xsT[kq * 4 + 3][row] = v.w;
        }
#pragma unroll
        for (int q = 0; q < 2; ++q) {            // stage W tile
            int fid = q * 256 + tid;
            int kr = fid >> 4, cq = fid & 15;
            *(float4*)&ws[kr][cq * 4] =
                *(const float4*)&W1[(size_t)(k0 + kr) * HID_DIM + cq * 4];
        }
        __syncthreads();
#pragma unroll
        for (int k = 0; k < 32; ++k) {
            float4 a = *(const float4*)&xsT[k][rbase];
            float4 w = *(const float4*)&ws[k][cbase];
            acc[0][0] += a.x * w.x; acc[0][1] += a.x * w.y; acc[0][2] += a.x * w.z; acc[0][3] += a.x * w.w;
            acc[1][0] += a.y * w.x; acc[1][1] += a.y * w.y; acc[1][2] += a.y * w.z; acc[1][3] += a.y * w.w;
            acc[2][0] += a.z * w.x; acc[2][1] += a.z * w.y; acc[2][2] += a.z * w.z; acc[2][3] += a.z * w.w;
            acc[3][0] += a.w * w.x; acc[3][1] += a.w * w.y; acc[3][2] += a.w * w.z; acc[3][3] += a.w * w.w;
        }
    }
#pragma unroll
    for (int i = 0; i < 4; ++i) {
        int grow = row0 + rbase + i;
        if (grow < N_NODES) {
            union { __half2 h2v[2]; uint2 u; } pk;
            pk.h2v[0] = __floats2half2_rn(acc[i][0], acc[i][1]);
            pk.h2v[1] = __floats2half2_rn(acc[i][2], acc[i][3]);
            *(uint2*)&h1[(size_t)grow * HID_DIM + cbase] = pk.u;
        }
    }
}

// K5: gather aggregation DIM=64 (fp16 in, fp32 out), fused bias+ReLU.
// One wave per node, 2 edges in flight via lane-parity split.
__global__ __launch_bounds__(256) void k_agg_relu(const int* __restrict__ rowptr,
        const int* __restrict__ esrc, const float* __restrict__ dinv,
        const __half2* __restrict__ h,      // [N][32] half2
        const float* __restrict__ b,
        float* __restrict__ out) {
    int wid  = (int)((blockIdx.x * (size_t)blockDim.x + threadIdx.x) >> 6);
    int lane = threadIdx.x & 63;
    if (wid >= N_NODES) return;
    int p = lane >> 5;        // edge parity (0/1)
    int c = lane & 31;        // channel-pair index
    float dd = dinv[wid];
    float accx = 0.f, accy = 0.f;
    if (p == 0) {             // self-loop
        float2 v = __half22float2(h[(size_t)wid * 32 + c]);
        float w = dd * dd;
        accx += w * v.x; accy += w * v.y;
    }
    int beg = rowptr[wid], end = rowptr[wid + 1];
    int j = beg + p;
    for (; j + 2 < end; j += 4) {
        int s0 = esrc[j], s1 = esrc[j + 2];
        float w0 = dinv[s0] * dd, w1 = dinv[s1] * dd;
        float2 v0 = __half22float2(h[(size_t)s0 * 32 + c]);
        float2 v1 = __half22float2(h[(size_t)s1 * 32 + c]);
        accx += w0 * v0.x + w1 * v1.x;
        accy += w0 * v0.y + w1 * v1.y;
    }
    for (; j < end; j += 2) {
        int s = esrc[j];
        float w = dinv[s] * dd;
        float2 v = __half22float2(h[(size_t)s * 32 + c]);
        accx += w * v.x; accy += w * v.y;
    }
    accx += __shfl_xor(accx, 32);
    accy += __shfl_xor(accy, 32);
    if (p == 0) {
        float2 o;
        o.x = fmaxf(accx + b[c * 2 + 0], 0.f);
        o.y = fmaxf(accy + b[c * 2 + 1], 0.f);
        *(float2*)&out[(size_t)wid * HID_DIM + c * 2] = o;
    }
}

// K6: h2 = a @ W2  [50000,64]x[64,40], fp16 output — thread per (row, 4-col grp)
__global__ void k_gemm2(const float* __restrict__ a, const float* __restrict__ W2,
                        __half* __restrict__ h2) {
    int idx = blockIdx.x * blockDim.x + threadIdx.x;
    if (idx >= N_NODES * (OUT_DIM / 4)) return;
    int row = idx / (OUT_DIM / 4);
    int cg  = idx - row * (OUT_DIM / 4);
    const float* ar = a + (size_t)row * HID_DIM;
    float4 acc = make_float4(0.f, 0.f, 0.f, 0.f);
#pragma unroll
    for (int k = 0; k < HID_DIM; ++k) {
        float ak = ar[k];
        float4 w = *(const float4*)&W2[k * OUT_DIM + cg * 4];
        acc.x += ak * w.x; acc.y += ak * w.y; acc.z += ak * w.z; acc.w += ak * w.w;
    }
    union { __half2 h2v[2]; uint2 u; } pk;
    pk.h2v[0] = __floats2half2_rn(acc.x, acc.y);
    pk.h2v[1] = __floats2half2_rn(acc.z, acc.w);
    *(uint2*)&h2[(size_t)row * OUT_DIM + cg * 4] = pk.u;
}

// K7: gather aggregation DIM=40 (fp16 in), fused bias + log_softmax.
// One wave per node, 2 edges in flight via lane-parity split.
__global__ __launch_bounds__(256) void k_agg_lsm(const int* __restrict__ rowptr,
        const int* __restrict__ esrc, const float* __restrict__ dinv,
        const __half2* __restrict__ h,      // [N][20] half2
        const float* __restrict__ b,
        float* __restrict__ out) {
    int wid  = (int)((blockIdx.x * (size_t)blockDim.x + threadIdx.x) >> 6);
    int lane = threadIdx.x & 63;
    if (wid >= N_NODES) return;
    int p = lane >> 5;
    int c = lane & 31;
    bool act = (c < OUT_DIM / 2);
    float dd = dinv[wid];
    float accx = 0.f, accy = 0.f;
    if (p == 0 && act) {      // self-loop
        float2 v = __half22float2(h[(size_t)wid * 20 + c]);
        float w = dd * dd;
        accx += w * v.x; accy += w * v.y;
    }
    int beg = rowptr[wid], end = rowptr[wid + 1];
    int j = beg + p;
    for (; j + 2 < end; j += 4) {
        int s0 = esrc[j], s1 = esrc[j + 2];
        float w0 = dinv[s0] * dd, w1 = dinv[s1] * dd;
        if (act) {
            float2 v0 = __half22float2(h[(size_t)s0 * 20 + c]);
            float2 v1 = __half22float2(h[(size_t)s1 * 20 + c]);
            accx += w0 * v0.x + w1 * v1.x;
            accy += w0 * v0.y + w1 * v1.y;
        }
    }
    for (; j < end; j += 2) {
        int s = esrc[j];
        float w = dinv[s] * dd;
        if (act) {
            float2 v = __half22float2(h[(size_t)s * 20 + c]);
            accx += w * v.x; accy += w * v.y;
        }
    }
    accx += __shfl_xor(accx, 32);   // both parity groups now hold full sums
    accy += __shfl_xor(accy, 32);
    float vx = act ? accx + b[c * 2 + 0] : -INFINITY;
    float vy = act ? accy + b[c * 2 + 1] : -INFINITY;
    float m = fmaxf(vx, vy);
    for (int o = 16; o; o >>= 1) m = fmaxf(m, __shfl_xor(m, o));
    float ex = act ? (__expf(vx - m) + __expf(vy - m)) : 0.f;
    float ssum = ex;
    for (int o = 16; o; o >>= 1) ssum += __shfl_xor(ssum, o);
    float ls = __logf(ssum);
    if (p == 0 && act) {
        float2 o2 = make_float2(vx - m - ls, vy - m - ls);
        *(float2*)&out[(size_t)wid * OUT_DIM + c * 2] = o2;
    }
}

extern "C" void kernel_launch(void* const* d_in, const int* in_sizes, int n_in,
                              void* d_out, int out_size, void* d_ws, size_t ws_size,
                              hipStream_t stream) {
    const float* x    = (const float*)d_in[0];
    const int*   ei   = (const int*)d_in[1];
    const int*   srcp = ei;             // edge_index[0]
    const int*   dstp = ei + N_EDGES;   // edge_index[1]
    const float* W1   = (const float*)d_in[2];
    const float* b1   = (const float*)d_in[3];
    const float* W2   = (const float*)d_in[4];
    const float* b2   = (const float*)d_in[5];
    float* out = (float*)d_out;

    // workspace layout (~34 MB)
    char* p = (char*)d_ws;
    int*    cnt    = (int*)p;    p += (size_t)N_NODES * 4;
    int*    rowptr = (int*)p;    p += (size_t)(N_NODES + 4) * 4;
    int*    rank_  = (int*)p;    p += (size_t)N_EDGES * 4;
    int*    bsum   = (int*)p;    p += 256 * 4;
    int*    esrc   = (int*)p;    p += (size_t)N_EDGES * 4;
    float*  dinv   = (float*)p;  p += (size_t)N_NODES * 4;
    __half* h1     = (__half*)p; p += (size_t)N_NODES * HID_DIM * 2;
    float*  agg1   = (float*)p;  p += (size_t)N_NODES * HID_DIM * 4;
    __half* h2     = (__half*)p; p += (size_t)N_NODES * OUT_DIM * 2;

    hipMemsetAsync(cnt, 0, (size_t)N_NODES * 4, stream);

    const int NBLK = (N_NODES + 255) / 256;  // 196

    k_count<<<(N_EDGES + 255) / 256, 256, 0, stream>>>(dstp, cnt, rank_, N_EDGES);
    k_scan1<<<NBLK, 256, 0, stream>>>(cnt, rowptr, bsum);
    k_scan2<<<1, 256, 0, stream>>>(bsum, NBLK);
    k_scan3_dinv<<<NBLK, 256, 0, stream>>>(rowptr, bsum, cnt, dinv);
    k_fill<<<(N_EDGES + 255) / 256, 256, 0, stream>>>(srcp, dstp, rowptr, rank_, esrc, N_EDGES);

    k_gemm1<<<(N_NODES + 63) / 64, 256, 0, stream>>>(x, W1, h1);

    k_agg_relu<<<(N_NODES + 3) / 4, 256, 0, stream>>>(rowptr, esrc, dinv,
                                                      (const __half2*)h1, b1, agg1);

    k_gemm2<<<(N_NODES * (OUT_DIM / 4) + 255) / 256, 256, 0, stream>>>(agg1, W2, h2);

    k_agg_lsm<<<(N_NODES + 3) / 4, 256, 0, stream>>>(rowptr, esrc, dinv,
                                                     (const __half2*)h2, b2, out);
}

// Round 5
// 176.114 us; speedup vs baseline: 2.7543x; 1.0948x over previous
//
#include <hip/hip_runtime.h>
#include <hip/hip_bf16.h>
#include <hip/hip_fp16.h>
#include <cstddef>

#define N_NODES 50000
#define IN_DIM 256
#define HID_DIM 64
#define OUT_DIM 40
#define N_EDGES 800000

// ---------------------------------------------------------------------------
// K0: zero the histogram (hipMemsetAsync's fill node measured 41 us!)
__global__ void k_zero(int* __restrict__ cnt) {
    int i = blockIdx.x * 256 + threadIdx.x;
    if (i < N_NODES) cnt[i] = 0;
}

// K1: degree histogram over dst; atomicAdd return value = rank of edge in its
// dst bucket (saves a second atomic pass in fill).
__global__ void k_count(const int* __restrict__ dst, int* __restrict__ cnt,
                        int* __restrict__ rank_, int E) {
    int i = blockIdx.x * blockDim.x + threadIdx.x;
    if (i < E) rank_[i] = atomicAdd(&cnt[dst[i]], 1);
}

// K2a: per-block exclusive scan of cnt -> rowptr (block-local) + block sums
__global__ void k_scan1(const int* __restrict__ cnt, int* __restrict__ excl,
                        int* __restrict__ bsum) {
    __shared__ int wsum[4];
    int i = blockIdx.x * 256 + threadIdx.x;
    int lane = threadIdx.x & 63, w = threadIdx.x >> 6;
    int v = (i < N_NODES) ? cnt[i] : 0;
    int inc = v;
    for (int o = 1; o < 64; o <<= 1) {
        int t = __shfl_up(inc, o);
        if (lane >= o) inc += t;
    }
    if (lane == 63) wsum[w] = inc;
    __syncthreads();
    int off = 0;
    for (int k = 0; k < w; ++k) off += wsum[k];
    if (i < N_NODES) excl[i] = off + inc - v;
    if (threadIdx.x == 255) bsum[blockIdx.x] = off + inc;
}

// K2b: single-block exclusive scan of the block sums (nb <= 256)
__global__ void k_scan2(int* __restrict__ bsum, int nb) {
    __shared__ int wsum[4];
    int i = threadIdx.x;
    int lane = i & 63, w = i >> 6;
    int v = (i < nb) ? bsum[i] : 0;
    int inc = v;
    for (int o = 1; o < 64; o <<= 1) {
        int t = __shfl_up(inc, o);
        if (lane >= o) inc += t;
    }
    if (lane == 63) wsum[w] = inc;
    __syncthreads();
    int off = 0;
    for (int k = 0; k < w; ++k) off += wsum[k];
    if (i < nb) bsum[i] = off + inc - v;
}

// K2c: add block offsets; append rowptr[N] = E; also dinv = rsqrt(deg+1)
__global__ void k_scan3_dinv(int* __restrict__ rowptr, const int* __restrict__ bsum,
                             const int* __restrict__ cnt, float* __restrict__ dinv) {
    int i = blockIdx.x * 256 + threadIdx.x;
    if (i < N_NODES) {
        rowptr[i] += bsum[blockIdx.x];
        dinv[i] = rsqrtf((float)cnt[i] + 1.0f);
    } else if (i == N_NODES) {
        rowptr[i] = N_EDGES;
    }
}

// K3: atomic-free bucket fill using precomputed rank
__global__ void k_fill(const int* __restrict__ src, const int* __restrict__ dst,
                       const int* __restrict__ rowptr, const int* __restrict__ rank_,
                       int* __restrict__ esrc, int E) {
    int i = blockIdx.x * blockDim.x + threadIdx.x;
    if (i < E) {
        int d = dst[i];
        esrc[rowptr[d] + rank_[i]] = src[i];
    }
}

// K4: g1 = dinv * (x @ W1)   [50000,256]x[256,64], fp16 output PRE-SCALED by
// dinv[row] so the aggregation never has to gather dinv[src].
__global__ __launch_bounds__(256) void k_gemm1(const float* __restrict__ x,
                                               const float* __restrict__ W1,
                                               const float* __restrict__ dinv,
                                               __half* __restrict__ g1) {
    __shared__ float xsT[32][68];   // [k][row], padded
    __shared__ float ws[32][64];    // [k][col]
    const int tid = threadIdx.x;
    const int row0 = blockIdx.x * 64;
    const int rbase = (tid >> 4) * 4;   // 0..60
    const int cbase = (tid & 15) * 4;   // 0..60
    float acc[4][4] = {};

    for (int k0 = 0; k0 < IN_DIM; k0 += 32) {
        __syncthreads();
#pragma unroll
        for (int q = 0; q < 2; ++q) {            // stage x tile (transposed)
            int fid = q * 256 + tid;             // 0..511
            int row = fid >> 3, kq = fid & 7;
            int grow = row0 + row;
            float4 v = make_float4(0.f, 0.f, 0.f, 0.f);
            if (grow < N_NODES)
                v = *(const float4*)&x[(size_t)grow * IN_DIM + k0 + kq * 4];
            xsT[kq * 4 + 0][row] = v.x;
            xsT[kq * 4 + 1][row] = v.y;
            xsT[kq * 4 + 2][row] = v.z;
            xsT[kq * 4 + 3][row] = v.w;
        }
#pragma unroll
        for (int q = 0; q < 2; ++q) {            // stage W tile
            int fid = q * 256 + tid;
            int kr = fid >> 4, cq = fid & 15;
            *(float4*)&ws[kr][cq * 4] =
                *(const float4*)&W1[(size_t)(k0 + kr) * HID_DIM + cq * 4];
        }
        __syncthreads();
#pragma unroll
        for (int k = 0; k < 32; ++k) {
            float4 a = *(const float4*)&xsT[k][rbase];
            float4 w = *(const float4*)&ws[k][cbase];
            acc[0][0] += a.x * w.x; acc[0][1] += a.x * w.y; acc[0][2] += a.x * w.z; acc[0][3] += a.x * w.w;
            acc[1][0] += a.y * w.x; acc[1][1] += a.y * w.y; acc[1][2] += a.y * w.z; acc[1][3] += a.y * w.w;
            acc[2][0] += a.z * w.x; acc[2][1] += a.z * w.y; acc[2][2] += a.z * w.z; acc[2][3] += a.z * w.w;
            acc[3][0] += a.w * w.x; acc[3][1] += a.w * w.y; acc[3][2] += a.w * w.z; acc[3][3] += a.w * w.w;
        }
    }
#pragma unroll
    for (int i = 0; i < 4; ++i) {
        int grow = row0 + rbase + i;
        if (grow < N_NODES) {
            float dv = dinv[grow];
            union { __half2 h2v[2]; uint2 u; } pk;
            pk.h2v[0] = __floats2half2_rn(acc[i][0] * dv, acc[i][1] * dv);
            pk.h2v[1] = __floats2half2_rn(acc[i][2] * dv, acc[i][3] * dv);
            *(uint2*)&g1[(size_t)grow * HID_DIM + cbase] = pk.u;
        }
    }
}

// K5: gather aggregation DIM=64 (pre-scaled fp16 in, fp32 out), fused bias+ReLU.
// One wave per node; 4 edges in flight (lane = parity p=lane>>4, uint2-chan
// c=lane&15); x2 unroll -> 8 outstanding gathers.
__global__ __launch_bounds__(256) void k_agg_relu(const int* __restrict__ rowptr,
        const int* __restrict__ esrc, const float* __restrict__ dinv,
        const uint2* __restrict__ g,        // [N][16] uint2 (=64 half)
        const float* __restrict__ b,
        float* __restrict__ out) {
    int wid  = (int)((blockIdx.x * (size_t)blockDim.x + threadIdx.x) >> 6);
    int lane = threadIdx.x & 63;
    if (wid >= N_NODES) return;
    int p = lane >> 4;        // edge parity 0..3
    int c = lane & 15;        // uint2 channel group
    float ax = 0.f, ay = 0.f, az = 0.f, aw = 0.f;
#define ACC_U2(v)  do {                                            \
        float2 f0 = __half22float2(*(const __half2*)&(v).x);       \
        float2 f1 = __half22float2(*(const __half2*)&(v).y);       \
        ax += f0.x; ay += f0.y; az += f1.x; aw += f1.y; } while (0)
    if (p == 0) { uint2 v = g[(size_t)wid * 16 + c]; ACC_U2(v); }  // self-loop
    int beg = rowptr[wid], end = rowptr[wid + 1];
    int j = beg + p;
    for (; j + 4 < end; j += 8) {
        int s0 = esrc[j], s1 = esrc[j + 4];
        uint2 v0 = g[(size_t)s0 * 16 + c];
        uint2 v1 = g[(size_t)s1 * 16 + c];
        ACC_U2(v0); ACC_U2(v1);
    }
    if (j < end) { uint2 v = g[(size_t)esrc[j] * 16 + c]; ACC_U2(v); }
    ax += __shfl_xor(ax, 16); ax += __shfl_xor(ax, 32);
    ay += __shfl_xor(ay, 16); ay += __shfl_xor(ay, 32);
    az += __shfl_xor(az, 16); az += __shfl_xor(az, 32);
    aw += __shfl_xor(aw, 16); aw += __shfl_xor(aw, 32);
    if (lane < 16) {
        float dd = dinv[wid];
        float4 bb = *(const float4*)&b[c * 4];
        float4 o;
        o.x = fmaxf(ax * dd + bb.x, 0.f);
        o.y = fmaxf(ay * dd + bb.y, 0.f);
        o.z = fmaxf(az * dd + bb.z, 0.f);
        o.w = fmaxf(aw * dd + bb.w, 0.f);
        *(float4*)&out[(size_t)wid * HID_DIM + c * 4] = o;
    }
#undef ACC_U2
}

// K6: g2 = dinv * (a @ W2)  [50000,64]x[64,40], pre-scaled fp16 output
__global__ void k_gemm2(const float* __restrict__ a, const float* __restrict__ W2,
                        const float* __restrict__ dinv, __half* __restrict__ g2) {
    int idx = blockIdx.x * blockDim.x + threadIdx.x;
    if (idx >= N_NODES * (OUT_DIM / 4)) return;
    int row = idx / (OUT_DIM / 4);
    int cg  = idx - row * (OUT_DIM / 4);
    const float* ar = a + (size_t)row * HID_DIM;
    float4 acc = make_float4(0.f, 0.f, 0.f, 0.f);
#pragma unroll
    for (int k = 0; k < HID_DIM; ++k) {
        float ak = ar[k];
        float4 w = *(const float4*)&W2[k * OUT_DIM + cg * 4];
        acc.x += ak * w.x; acc.y += ak * w.y; acc.z += ak * w.z; acc.w += ak * w.w;
    }
    float dv = dinv[row];
    union { __half2 h2v[2]; uint2 u; } pk;
    pk.h2v[0] = __floats2half2_rn(acc.x * dv, acc.y * dv);
    pk.h2v[1] = __floats2half2_rn(acc.z * dv, acc.w * dv);
    *(uint2*)&g2[(size_t)row * OUT_DIM + cg * 4] = pk.u;
}

// K7: gather aggregation DIM=40 (pre-scaled fp16 in), fused bias+log_softmax.
// Same 4-parity structure; channel groups c=0..9 active (10 uint2 per row).
__global__ __launch_bounds__(256) void k_agg_lsm(const int* __restrict__ rowptr,
        const int* __restrict__ esrc, const float* __restrict__ dinv,
        const uint2* __restrict__ g,        // [N][10] uint2 (=40 half)
        const float* __restrict__ b,
        float* __restrict__ out) {
    int wid  = (int)((blockIdx.x * (size_t)blockDim.x + threadIdx.x) >> 6);
    int lane = threadIdx.x & 63;
    if (wid >= N_NODES) return;
    int p = lane >> 4;
    int c = lane & 15;
    bool act = (c < 10);
    float ax = 0.f, ay = 0.f, az = 0.f, aw = 0.f;
#define ACC_U2(v)  do {                                            \
        float2 f0 = __half22float2(*(const __half2*)&(v).x);       \
        float2 f1 = __half22float2(*(const __half2*)&(v).y);       \
        ax += f0.x; ay += f0.y; az += f1.x; aw += f1.y; } while (0)
    if (p == 0 && act) { uint2 v = g[(size_t)wid * 10 + c]; ACC_U2(v); }
    int beg = rowptr[wid], end = rowptr[wid + 1];
    int j = beg + p;
    if (act) {
        for (; j + 4 < end; j += 8) {
            int s0 = esrc[j], s1 = esrc[j + 4];
            uint2 v0 = g[(size_t)s0 * 10 + c];
            uint2 v1 = g[(size_t)s1 * 10 + c];
            ACC_U2(v0); ACC_U2(v1);
        }
        if (j < end) { uint2 v = g[(size_t)esrc[j] * 10 + c]; ACC_U2(v); }
    }
    ax += __shfl_xor(ax, 16); ax += __shfl_xor(ax, 32);
    ay += __shfl_xor(ay, 16); ay += __shfl_xor(ay, 32);
    az += __shfl_xor(az, 16); az += __shfl_xor(az, 32);
    aw += __shfl_xor(aw, 16); aw += __shfl_xor(aw, 32);
    float dd = dinv[wid];
    float vx = -INFINITY, vy = -INFINITY, vz = -INFINITY, vw = -INFINITY;
    if (act) {
        float4 bb = *(const float4*)&b[c * 4];
        vx = ax * dd + bb.x; vy = ay * dd + bb.y;
        vz = az * dd + bb.z; vw = aw * dd + bb.w;
    }
    float m = fmaxf(fmaxf(vx, vy), fmaxf(vz, vw));
    for (int o = 8; o; o >>= 1) m = fmaxf(m, __shfl_xor(m, o));
    float es = act ? (__expf(vx - m) + __expf(vy - m) + __expf(vz - m) + __expf(vw - m)) : 0.f;
    for (int o = 8; o; o >>= 1) es += __shfl_xor(es, o);
    float ls = __logf(es);
    if (lane < 16 && act) {
        float4 o4 = make_float4(vx - m - ls, vy - m - ls, vz - m - ls, vw - m - ls);
        *(float4*)&out[(size_t)wid * OUT_DIM + c * 4] = o4;
    }
#undef ACC_U2
}

extern "C" void kernel_launch(void* const* d_in, const int* in_sizes, int n_in,
                              void* d_out, int out_size, void* d_ws, size_t ws_size,
                              hipStream_t stream) {
    const float* x    = (const float*)d_in[0];
    const int*   ei   = (const int*)d_in[1];
    const int*   srcp = ei;             // edge_index[0]
    const int*   dstp = ei + N_EDGES;   // edge_index[1]
    const float* W1   = (const float*)d_in[2];
    const float* b1   = (const float*)d_in[3];
    const float* W2   = (const float*)d_in[4];
    const float* b2   = (const float*)d_in[5];
    float* out = (float*)d_out;

    // workspace layout (~34 MB)
    char* p = (char*)d_ws;
    int*    cnt    = (int*)p;    p += (size_t)N_NODES * 4;
    int*    rowptr = (int*)p;    p += (size_t)(N_NODES + 4) * 4;
    int*    rank_  = (int*)p;    p += (size_t)N_EDGES * 4;
    int*    bsum   = (int*)p;    p += 256 * 4;
    int*    esrc   = (int*)p;    p += (size_t)N_EDGES * 4;
    float*  dinv   = (float*)p;  p += (size_t)N_NODES * 4;
    __half* g1     = (__half*)p; p += (size_t)N_NODES * HID_DIM * 2;
    float*  agg1   = (float*)p;  p += (size_t)N_NODES * HID_DIM * 4;
    __half* g2     = (__half*)p; p += (size_t)N_NODES * OUT_DIM * 2;

    const int NBLK = (N_NODES + 255) / 256;  // 196

    k_zero<<<NBLK, 256, 0, stream>>>(cnt);
    k_count<<<(N_EDGES + 255) / 256, 256, 0, stream>>>(dstp, cnt, rank_, N_EDGES);
    k_scan1<<<NBLK, 256, 0, stream>>>(cnt, rowptr, bsum);
    k_scan2<<<1, 256, 0, stream>>>(bsum, NBLK);
    k_scan3_dinv<<<NBLK, 256, 0, stream>>>(rowptr, bsum, cnt, dinv);
    k_fill<<<(N_EDGES + 255) / 256, 256, 0, stream>>>(srcp, dstp, rowptr, rank_, esrc, N_EDGES);

    k_gemm1<<<(N_NODES + 63) / 64, 256, 0, stream>>>(x, W1, dinv, g1);

    k_agg_relu<<<(N_NODES + 3) / 4, 256, 0, stream>>>(rowptr, esrc, dinv,
                                                      (const uint2*)g1, b1, agg1);

    k_gemm2<<<(N_NODES * (OUT_DIM / 4) + 255) / 256, 256, 0, stream>>>(agg1, W2, dinv, g2);

    k_agg_lsm<<<(N_NODES + 3) / 4, 256, 0, stream>>>(rowptr, esrc, dinv,
                                                     (const uint2*)g2, b2, out);
}